// Round 7
// baseline (170.262 us; speedup 1.0000x reference)
//
#include <hip/hip_runtime.h>
#include <math.h>

typedef float v2f __attribute__((ext_vector_type(2)));

#define NN 1024
#define IN_F 256
#define OUT_F 128
#define NHEADS 4
#define NHF 32

// K1: g_l/g_r = h @ W^T. Frozen structure from R5; one addition: gr is also
// written transposed (grT[h][fpair][j]) so K2 Phase C can read it coalesced.
__global__ void __launch_bounds__(256) glr_gemm(const float* __restrict__ hmat,
                                                const float* __restrict__ Wl,
                                                const float* __restrict__ Wr,
                                                v2f* __restrict__ glT,
                                                float* __restrict__ grh,
                                                v2f* __restrict__ grT) {
    __shared__ float hs[64 * 132];
    const int tid  = threadIdx.x;
    const int rg   = blockIdx.x;     // 0..15
    const int cs   = blockIdx.y;     // 0..31
    const int lane = tid & 63;
    const int wu   = __builtin_amdgcn_readfirstlane(tid >> 6);
    const int c0   = cs * 8 + wu * 2;
    const int half = c0 >> 7;
    const int cc   = c0 & 127;
    const float* __restrict__ W   = half ? Wr : Wl;
    const float* __restrict__ wr0 = W + cc * IN_F;
    const float* __restrict__ wr1 = wr0 + IN_F;

    float a0 = 0.f, a1 = 0.f;
    for (int kh = 0; kh < 2; ++kh) {
#pragma unroll
        for (int s = 0; s < 8; ++s) {
            const int v = tid + s * 256;
            const int row = v >> 5, q = v & 31;
            const float4 x = ((const float4*)hmat)[(rg * 64 + row) * 64 + kh * 32 + q];
            *(float4*)(hs + row * 132 + q * 4) = x;
        }
        __syncthreads();
        const float4* __restrict__ w0p = (const float4*)(wr0 + kh * 128);
        const float4* __restrict__ w1p = (const float4*)(wr1 + kh * 128);
        const float*  __restrict__ hrow = hs + lane * 132;
#pragma unroll 8
        for (int q = 0; q < 32; ++q) {
            const float4 hv = *(const float4*)(hrow + q * 4);
            const float4 w0 = w0p[q];
            const float4 w1 = w1p[q];
            a0 = fmaf(hv.x, w0.x, fmaf(hv.y, w0.y, fmaf(hv.z, w0.z, fmaf(hv.w, w0.w, a0))));
            a1 = fmaf(hv.x, w1.x, fmaf(hv.y, w1.y, fmaf(hv.z, w1.z, fmaf(hv.w, w1.w, a1))));
        }
        __syncthreads();
    }

    const int row = rg * 64 + lane;
    const int hh = cc >> 5, f0 = cc & 31;
    if (half == 0) {
        glT[(hh * 16 + (f0 >> 1)) * NN + row] = (v2f){a0, a1};
    } else {
        *(v2f*)(grh + (hh * NN + row) * NHF + f0) = (v2f){a0, a1};
        grT[(hh * 16 + (f0 >> 1)) * NN + row] = (v2f){a0, a1};
    }
}

// K2 v4: i-tile = 16 per block. Grid (64 i-tiles, 4 heads) = 256 blocks (1/CU),
// 512 thr. Phase A: lane<->j, gl tile in 32 VGPRs loaded ONCE per 512-j chunk,
// inner loop over 16 i reusing it (global loads cut 32x vs R6); gr rows from
// LDS broadcast; alpha_j computed in-thread. p -> p_buf[16][1024] LDS.
// Phase C: wave<->f-quad, lane<->j, gr read coalesced from grT (no staging, no
// barriers); row-sums folded into the p reads; 6-round butterfly epilogue.
__global__ void __launch_bounds__(512, 2) gat_main(const v2f* __restrict__ glT,
                                                   const float* __restrict__ grh,
                                                   const v2f* __restrict__ grT,
                                                   const int* __restrict__ adj,
                                                   const float* __restrict__ attn_w,
                                                   float* __restrict__ out) {
    const int hh   = blockIdx.y;
    const int i0   = blockIdx.x * 16;
    const int tid  = threadIdx.x;
    const int lane = tid & 63;
    const int wv   = __builtin_amdgcn_readfirstlane(tid >> 6);

    __shared__ float p_buf[16][NN];   // 64 KB
    __shared__ float grt[16][NHF];    // 2 KB, read broadcast-uniform

    // stage the 16 gr rows for this i-tile (contiguous 512 floats)
    if (tid < 16 * NHF) ((float*)grt)[tid] = grh[(hh * NN + i0) * NHF + tid];

    const v2f* __restrict__ w2p    = (const v2f*)attn_w;
    const v2f* __restrict__ glbase = glT + hh * 16 * NN;
    __syncthreads();

    // ---- Phase A ----
    for (int c = 0; c < 2; ++c) {
        const int j = (c << 9) + tid;
        const v2f* __restrict__ glp = glbase + j;
        v2f gl2[16];
#pragma unroll
        for (int fp = 0; fp < 16; ++fp) gl2[fp] = glp[fp * NN];   // coalesced, once per c

        v2f aa = {0.f, 0.f};
#pragma unroll
        for (int fp = 0; fp < 16; ++fp) aa += gl2[fp] * w2p[fp];
        const float alpha6 = 0.6f * (aa.x + aa.y);

        int adjv[16];
#pragma unroll
        for (int ii = 0; ii < 16; ++ii) adjv[ii] = adj[(i0 + ii) * NN + j];

#pragma unroll
        for (int ii = 0; ii < 16; ++ii) {
            const v2f* __restrict__ grp = (const v2f*)grt[ii];    // uniform -> broadcast
            v2f S = {0.f, 0.f};
#pragma unroll
            for (int fp = 0; fp < 16; ++fp) {
                const v2f s = gl2[fp] + grp[fp];
                const v2f m = __builtin_elementwise_max(s, -s);
                S += m * w2p[fp];
            }
            const float e = fmaf(0.4f, S.x + S.y, alpha6);
            p_buf[ii][j] = adjv[ii] ? __expf(e) : 0.f;
        }
    }
    __syncthreads();

    // ---- Phase C: o[ii, f-quad(wv)] = sum_j p * gr ----
    const v2f* __restrict__ g0p = grT + (hh * 16 + wv * 2 + 0) * NN;
    const v2f* __restrict__ g1p = grT + (hh * 16 + wv * 2 + 1) * NN;
    v2f acc[16][2];
    float lsum[16];
#pragma unroll
    for (int ii = 0; ii < 16; ++ii) {
        acc[ii][0] = (v2f){0.f, 0.f};
        acc[ii][1] = (v2f){0.f, 0.f};
        lsum[ii] = 0.f;
    }
    for (int g = 0; g < 16; ++g) {
        const int jq = (g << 6) + lane;
        const v2f g01 = g0p[jq];                 // 8 B/lane coalesced
        const v2f g23 = g1p[jq];
        float pv[16];
#pragma unroll
        for (int ii = 0; ii < 16; ++ii) pv[ii] = p_buf[ii][jq];   // lane-contig b32
#pragma unroll
        for (int ii = 0; ii < 16; ++ii) {
            const v2f pp = {pv[ii], pv[ii]};
            acc[ii][0] += pp * g01;
            acc[ii][1] += pp * g23;
            lsum[ii] += pv[ii];
        }
    }

    // butterfly: 64 acc floats + 16 sums over the 64 j-lanes
    float rv[80];
#pragma unroll
    for (int ii = 0; ii < 16; ++ii) {
        rv[ii * 4 + 0] = acc[ii][0].x;  rv[ii * 4 + 1] = acc[ii][0].y;
        rv[ii * 4 + 2] = acc[ii][1].x;  rv[ii * 4 + 3] = acc[ii][1].y;
        rv[64 + ii] = lsum[ii];
    }
#pragma unroll
    for (int d = 32; d > 0; d >>= 1) {
#pragma unroll
        for (int k = 0; k < 80; ++k) rv[k] += __shfl_xor(rv[k], d);
    }
    if (lane == 0) {
#pragma unroll
        for (int ii = 0; ii < 16; ++ii) {
            const float inv = 1.f / rv[64 + ii];
            const float x0 = rv[ii * 4 + 0] * inv;
            const float x1 = rv[ii * 4 + 1] * inv;
            const float x2 = rv[ii * 4 + 2] * inv;
            const float x3 = rv[ii * 4 + 3] * inv;
            float4 r;
            r.x = (x0 > 0.f) ? x0 : (__expf(x0) - 1.f);
            r.y = (x1 > 0.f) ? x1 : (__expf(x1) - 1.f);
            r.z = (x2 > 0.f) ? x2 : (__expf(x2) - 1.f);
            r.w = (x3 > 0.f) ? x3 : (__expf(x3) - 1.f);
            *(float4*)(out + (i0 + ii) * OUT_F + hh * NHF + (wv << 2)) = r;
        }
    }
}

extern "C" void kernel_launch(void* const* d_in, const int* in_sizes, int n_in,
                              void* d_out, int out_size, void* d_ws, size_t ws_size,
                              hipStream_t stream) {
    const float* hmat = (const float*)d_in[0];
    const int*   adj  = (const int*)d_in[1];
    const float* Wl   = (const float*)d_in[2];
    const float* Wr   = (const float*)d_in[3];
    const float* aw   = (const float*)d_in[4];
    float* o          = (float*)d_out;

    float* wsf = (float*)d_ws;
    v2f*   glT = (v2f*)wsf;                          // [4][16][1024] v2f = 512 KB
    float* grh = wsf + NHEADS * 16 * NN * 2;         // [4][1024][32] = 512 KB
    v2f*   grT = (v2f*)(grh + NHEADS * NN * NHF);    // [4][16][1024] v2f = 512 KB

    glr_gemm<<<dim3(16, 32), dim3(256), 0, stream>>>(hmat, Wl, Wr, glT, grh, grT);
    gat_main<<<dim3(NN / 16, NHEADS), dim3(512), 0, stream>>>(glT, grh, grT, adj, aw, o);
}

// Round 8
// 130.088 us; speedup vs baseline: 1.3088x; 1.3088x over previous
//
#include <hip/hip_runtime.h>
#include <math.h>

typedef float v2f __attribute__((ext_vector_type(2)));

#define NN 1024
#define IN_F 256
#define OUT_F 128
#define NHEADS 4
#define NHF 32

// K1: core frozen from R5. New output layout: chunked glC/grC[h][chunk16][fp16][lane64]
// (v2f) so K2's 16 inner loads per j-chunk share ONE base register with 13-bit
// immediate offsets fp*512B. grh kept row-major for K2's wave-uniform gr loads.
__global__ void __launch_bounds__(256) glr_gemm(const float* __restrict__ hmat,
                                                const float* __restrict__ Wl,
                                                const float* __restrict__ Wr,
                                                v2f* __restrict__ glC,
                                                float* __restrict__ grh,
                                                v2f* __restrict__ grC) {
    __shared__ float hs[64 * 132];
    const int tid  = threadIdx.x;
    const int rg   = blockIdx.x;     // 0..15 == j-chunk
    const int cs   = blockIdx.y;     // 0..31
    const int lane = tid & 63;
    const int wu   = __builtin_amdgcn_readfirstlane(tid >> 6);
    const int c0   = cs * 8 + wu * 2;
    const int half = c0 >> 7;
    const int cc   = c0 & 127;
    const float* __restrict__ W   = half ? Wr : Wl;
    const float* __restrict__ wr0 = W + cc * IN_F;
    const float* __restrict__ wr1 = wr0 + IN_F;

    float a0 = 0.f, a1 = 0.f;
    for (int kh = 0; kh < 2; ++kh) {
#pragma unroll
        for (int s = 0; s < 8; ++s) {
            const int v = tid + s * 256;
            const int row = v >> 5, q = v & 31;
            const float4 x = ((const float4*)hmat)[(rg * 64 + row) * 64 + kh * 32 + q];
            *(float4*)(hs + row * 132 + q * 4) = x;
        }
        __syncthreads();
        const float4* __restrict__ w0p = (const float4*)(wr0 + kh * 128);
        const float4* __restrict__ w1p = (const float4*)(wr1 + kh * 128);
        const float*  __restrict__ hrow = hs + lane * 132;
#pragma unroll 8
        for (int q = 0; q < 32; ++q) {
            const float4 hv = *(const float4*)(hrow + q * 4);
            const float4 w0 = w0p[q];
            const float4 w1 = w1p[q];
            a0 = fmaf(hv.x, w0.x, fmaf(hv.y, w0.y, fmaf(hv.z, w0.z, fmaf(hv.w, w0.w, a0))));
            a1 = fmaf(hv.x, w1.x, fmaf(hv.y, w1.y, fmaf(hv.z, w1.z, fmaf(hv.w, w1.w, a1))));
        }
        __syncthreads();
    }

    const int row = rg * 64 + lane;
    const int hh = cc >> 5, fp = (cc & 31) >> 1;
    if (half == 0) {
        glC[((hh * 16 + rg) * 16 + fp) * 64 + lane] = (v2f){a0, a1};
    } else {
        *(v2f*)(grh + (hh * NN + row) * NHF + (cc & 31)) = (v2f){a0, a1};
        grC[((hh * 16 + rg) * 16 + fp) * 64 + lane] = (v2f){a0, a1};
    }
}

// K2 v5: block = 1024 thr (16 waves), wave <-> (ii 0..7, j-half 0..1).
// i-tile 8 per block; grid (128,4). LDS ~39 KB -> 2 blocks/CU = 32 waves/CU
// (100% nominal occupancy; launch_bounds(1024,8) caps VGPR at 64 -- R6's
// identical core compiled to 48).
// Phase A: gr row in SGPRs (wave-uniform), gl chunk loads = 1 base + imm
// offsets, alpha from a cooperative pre-pass; p -> p_buf[8][1024].
// Phase C: wave <-> (f-quad, j-half), acc[8][2]; gr coalesced from grC;
// butterfly + 2 KB LDS cross-half combine; /l + ELU.
__global__ void __launch_bounds__(1024, 8) gat_main(const v2f* __restrict__ glC,
                                                    const float* __restrict__ grh,
                                                    const v2f* __restrict__ grC,
                                                    const int* __restrict__ adj,
                                                    const float* __restrict__ attn_w,
                                                    float* __restrict__ out) {
    const int hh   = blockIdx.y;
    const int i0   = blockIdx.x * 8;
    const int tid  = threadIdx.x;
    const int lane = tid & 63;
    const int wv   = __builtin_amdgcn_readfirstlane(tid >> 6);  // 0..15
    const int ii   = wv & 7;        // Phase A row / Phase C f-quad
    const int hf   = wv >> 3;       // j-half

    __shared__ float p_buf[8][NN];       // 32 KB
    __shared__ float alpha_s[NN];        // 4 KB
    __shared__ float lpart[8][2];
    __shared__ float l_sh[8];
    __shared__ float opart[2][8][8][4];  // 2 KB [hf][q][ii][fr]

    const v2f* __restrict__ w2p = (const v2f*)attn_w;

    // ---- alpha pre-pass: tid <-> j ----
    {
        const int ch = tid >> 6;
        const v2f* __restrict__ gp = glC + ((hh * 16 + ch) * 16) * 64 + (tid & 63);
        v2f aa = {0.f, 0.f};
#pragma unroll
        for (int fp = 0; fp < 16; ++fp) aa += gp[fp * 64] * w2p[fp];
        alpha_s[tid] = 0.6f * (aa.x + aa.y);
    }

    // gr row for this wave's ii (wave-uniform -> SGPRs)
    const v2f* __restrict__ gr2 = (const v2f*)(grh + (hh * NN + i0 + ii) * NHF);
    v2f grr[16];
#pragma unroll
    for (int fp = 0; fp < 16; ++fp) grr[fp] = gr2[fp];

    __syncthreads();

    // ---- Phase A: 8 chunks of 64 j in this wave's half ----
    const int* __restrict__ adjrow = adj + (i0 + ii) * NN + (hf << 9);
    float* __restrict__ prow = &p_buf[ii][hf << 9];
    const float* __restrict__ arow = &alpha_s[hf << 9];
    float lsum = 0.f;
    for (int g = 0; g < 8; ++g) {
        const int jl = (g << 6) + lane;
        const v2f* __restrict__ gp = glC + ((hh * 16 + (hf << 3) + g) * 16) * 64 + lane;
        v2f gl2[16];
#pragma unroll
        for (int fp = 0; fp < 16; ++fp) gl2[fp] = gp[fp * 64];   // imm offsets fp*512B
        const int ad = adjrow[jl];
        v2f S = {0.f, 0.f};
#pragma unroll
        for (int fp = 0; fp < 16; ++fp) {
            const v2f s = gl2[fp] + grr[fp];
            const v2f m = __builtin_elementwise_max(s, -s);
            S += m * w2p[fp];
        }
        const float e = fmaf(0.4f, S.x + S.y, arow[jl]);
        const float p = ad ? __expf(e) : 0.f;
        prow[jl] = p;
        lsum += p;
    }
#pragma unroll
    for (int d = 32; d > 0; d >>= 1) lsum += __shfl_xor(lsum, d);
    if (lane == 0) lpart[ii][hf] = lsum;
    __syncthreads();
    if (tid < 8) l_sh[tid] = lpart[tid][0] + lpart[tid][1];

    // ---- Phase C: wave (q=ii, hf); f-quad q, j-half hf ----
    v2f acc[8][2];
#pragma unroll
    for (int k = 0; k < 8; ++k) { acc[k][0] = (v2f){0.f, 0.f}; acc[k][1] = (v2f){0.f, 0.f}; }
    const int q = ii;
    for (int g = 0; g < 8; ++g) {
        const int ch = (hf << 3) + g;
        const v2f* __restrict__ gp = grC + ((hh * 16 + ch) * 16) * 64 + lane;
        const v2f g01 = gp[(2 * q) * 64];          // imm offsets
        const v2f g23 = gp[(2 * q + 1) * 64];
        const float* __restrict__ pb = &p_buf[0][(ch << 6) + lane];
        float pv[8];
#pragma unroll
        for (int k = 0; k < 8; ++k) pv[k] = pb[k * NN];          // ds imm offsets k*4096B
#pragma unroll
        for (int k = 0; k < 8; ++k) {
            const v2f pp = {pv[k], pv[k]};
            acc[k][0] += pp * g01;
            acc[k][1] += pp * g23;
        }
    }

    float rv[32];
#pragma unroll
    for (int k = 0; k < 8; ++k) {
        rv[k * 4 + 0] = acc[k][0].x;  rv[k * 4 + 1] = acc[k][0].y;
        rv[k * 4 + 2] = acc[k][1].x;  rv[k * 4 + 3] = acc[k][1].y;
    }
#pragma unroll
    for (int d = 32; d > 0; d >>= 1) {
#pragma unroll
        for (int k = 0; k < 32; ++k) rv[k] += __shfl_xor(rv[k], d);
    }
    if (lane == 0) {
#pragma unroll
        for (int k = 0; k < 8; ++k) {
            opart[hf][q][k][0] = rv[k * 4 + 0];
            opart[hf][q][k][1] = rv[k * 4 + 1];
            opart[hf][q][k][2] = rv[k * 4 + 2];
            opart[hf][q][k][3] = rv[k * 4 + 3];
        }
    }
    __syncthreads();

    if (tid < 256) {
        const int io = tid >> 5, ff = tid & 31;
        const float o = (opart[0][ff >> 2][io][ff & 3] + opart[1][ff >> 2][io][ff & 3])
                        / l_sh[io];
        const float r = (o > 0.f) ? o : (__expf(o) - 1.f);
        out[(i0 + io) * OUT_F + hh * NHF + ff] = r;
    }
}

extern "C" void kernel_launch(void* const* d_in, const int* in_sizes, int n_in,
                              void* d_out, int out_size, void* d_ws, size_t ws_size,
                              hipStream_t stream) {
    const float* hmat = (const float*)d_in[0];
    const int*   adj  = (const int*)d_in[1];
    const float* Wl   = (const float*)d_in[2];
    const float* Wr   = (const float*)d_in[3];
    const float* aw   = (const float*)d_in[4];
    float* o          = (float*)d_out;

    float* wsf = (float*)d_ws;
    v2f*   glC = (v2f*)wsf;                  // [4][16][16][64] v2f = 512 KB
    float* grh = wsf + 131072;               // [4][1024][32]   = 512 KB
    v2f*   grC = (v2f*)(wsf + 262144);       // [4][16][16][64] v2f = 512 KB

    glr_gemm<<<dim3(16, 32), dim3(256), 0, stream>>>(hmat, Wl, Wr, glC, grh, grC);
    gat_main<<<dim3(NN / 8, NHEADS), dim3(1024), 0, stream>>>(glC, grh, grC, adj, aw, o);
}